// Round 1
// baseline (139.427 us; speedup 1.0000x reference)
//
#include <hip/hip_runtime.h>

// Matcher: anchors [N=1024,2] fp32, gt_boxes [B=128,M=256,4] fp32.
// Both boxes are origin-centered in the reference math, so:
//   iw = min(aw, gtw), ih = min(ah, gth)
//   iou = iw*ih / (aw*ah + gtw*gth - iw*ih)
// Outputs (concatenated float32): matches [B,M] (argmax over N, first-max
// semantics), then ious [B,N,M].
//
// Write-BW-bound kernel (~134 MB out). One block per (b, m-half): argmax over
// the full N stays inside a block -> no workspace. 8 waves/block, each wave
// owns a 128-wide n chunk; each lane owns 2 adjacent m -> float2 stores
// (512 B contiguous per wave per n). Anchors staged in LDS (broadcast reads).

#define N_ANCH 1024
#define B_SZ   128
#define M_SZ   256
#define NWAVES 8
#define NPW    (N_ANCH / NWAVES)   // 128 n per wave

__global__ __launch_bounds__(512) void matcher_kernel(
    const float* __restrict__ anchors,   // [N,2]
    const float* __restrict__ gt,        // [B,M,4]
    float* __restrict__ out)             // [B*M] matches ++ [B,N,M] ious
{
    __shared__ float2 s_anch[N_ANCH];          // 8 KB
    __shared__ float  s_val[NWAVES * 128];     // 4 KB
    __shared__ int    s_idx[NWAVES * 128];     // 4 KB

    const int tid  = threadIdx.x;
    const int lane = tid & 63;
    const int w    = tid >> 6;
    const int b    = blockIdx.x >> 1;
    const int half = blockIdx.x & 1;

    // Stage all anchors into LDS (each block needs the full N range).
    const float2* a2 = (const float2*)anchors;
    for (int i = tid; i < N_ANCH; i += 512) s_anch[i] = a2[i];

    // Per-thread gt boxes (two adjacent m).
    const int m0 = half * 128 + lane * 2;
    const float4* g4 = (const float4*)gt;
    float4 g0 = g4[b * M_SZ + m0];
    float4 g1 = g4[b * M_SZ + m0 + 1];
    const float gtw0 = g0.z - g0.x, gth0 = g0.w - g0.y;
    const float gtw1 = g1.z - g1.x, gth1 = g1.w - g1.y;
    const float areab0 = gtw0 * gth0, areab1 = gtw1 * gth1;

    __syncthreads();

    float bv0 = -1.0f, bv1 = -1.0f;
    int   bi0 = 0,     bi1 = 0;
    float* __restrict__ ious = out + (size_t)B_SZ * M_SZ;
    const int n_begin = w * NPW;
    float* __restrict__ row = ious + (size_t)(b * N_ANCH + n_begin) * M_SZ + m0;

    #pragma unroll 4
    for (int n = n_begin; n < n_begin + NPW; ++n) {
        float2 a = s_anch[n];            // wave-uniform -> LDS broadcast
        float areaa = a.x * a.y;

        float iw0 = fminf(a.x, gtw0), ih0 = fminf(a.y, gth0);
        float inter0 = iw0 * ih0;
        float iou0 = __fdividef(inter0, areaa + areab0 - inter0);

        float iw1 = fminf(a.x, gtw1), ih1 = fminf(a.y, gth1);
        float inter1 = iw1 * ih1;
        float iou1 = __fdividef(inter1, areaa + areab1 - inter1);

        if (iou0 > bv0) { bv0 = iou0; bi0 = n; }   // strict > keeps first max
        if (iou1 > bv1) { bv1 = iou1; bi1 = n; }

        *(float2*)row = make_float2(iou0, iou1);
        row += M_SZ;
    }

    // Per-wave partials -> LDS.
    s_val[w * 128 + lane * 2]     = bv0;
    s_idx[w * 128 + lane * 2]     = bi0;
    s_val[w * 128 + lane * 2 + 1] = bv1;
    s_idx[w * 128 + lane * 2 + 1] = bi1;
    __syncthreads();

    // Reduce the 8 wave-partials per m; ascending wave order + strict >
    // preserves argmax first-occurrence semantics.
    if (tid < 128) {
        float bv = s_val[tid];
        int   bi = s_idx[tid];
        for (int ww = 1; ww < NWAVES; ++ww) {
            float v = s_val[ww * 128 + tid];
            int   ix = s_idx[ww * 128 + tid];
            if (v > bv) { bv = v; bi = ix; }
        }
        out[b * M_SZ + half * 128 + tid] = (float)bi;
    }
}

extern "C" void kernel_launch(void* const* d_in, const int* in_sizes, int n_in,
                              void* d_out, int out_size, void* d_ws, size_t ws_size,
                              hipStream_t stream) {
    const float* anchors = (const float*)d_in[0];   // [1024,2]
    const float* gt      = (const float*)d_in[1];   // [128,256,4]
    float* out = (float*)d_out;

    dim3 grid(B_SZ * 2);   // 256 blocks: (b, m-half)
    dim3 block(512);
    matcher_kernel<<<grid, block, 0, stream>>>(anchors, gt, out);
}